// Round 1
// baseline (987.199 us; speedup 1.0000x reference)
//
#include <hip/hip_runtime.h>
#include <math.h>

#define PRE_NMS 2000
#define POST_NMS 1000
#define IOU_T 0.7f
#define IMGSZ 800.0f
#define CAP 8192            // candidate buffer per image (expected ~3.6k)
#define NBINS 1024          // top-10 bits of monotone key
#define NWORDS 32           // ceil(PRE_NMS/64)

__device__ __forceinline__ unsigned key_of(float f) {
    unsigned u = __float_as_uint(f);
    return (u & 0x80000000u) ? ~u : (u | 0x80000000u);
}
__device__ __forceinline__ float inv_key(unsigned k) {
    unsigned u = (k & 0x80000000u) ? (k ^ 0x80000000u) : ~k;
    return __uint_as_float(u);
}

// ---------------- stage 1: per-image histogram threshold + compact ----------
__global__ __launch_bounds__(1024) void topk_select(
    const float* __restrict__ scores, int A,
    unsigned long long* __restrict__ cand, int* __restrict__ cand_cnt) {
  int b = blockIdx.x;
  __shared__ unsigned hist[NBINS];
  __shared__ unsigned tmp[NBINS];
  __shared__ int s_thresh;
  __shared__ int s_cnt;
  int tid = threadIdx.x;
  hist[tid] = 0;
  if (tid == 0) s_cnt = 0;
  __syncthreads();
  const float* sc = scores + (size_t)b * A;
  for (int i = tid; i < A; i += 1024)
    atomicAdd(&hist[key_of(sc[i]) >> 22], 1u);
  __syncthreads();
  // suffix sum over bins (Hillis-Steele)
  unsigned v = hist[tid];
  for (int d = 1; d < NBINS; d <<= 1) {
    tmp[tid] = v;
    __syncthreads();
    if (tid + d < NBINS) v += tmp[tid + d];
    __syncthreads();
  }
  tmp[tid] = v;             // v = count of keys with bin >= tid
  __syncthreads();
  unsigned nextv = (tid < NBINS - 1) ? tmp[tid + 1] : 0u;
  if (v >= PRE_NMS && nextv < PRE_NMS) s_thresh = tid;  // unique crossing
  __syncthreads();
  int T = s_thresh;
  unsigned long long* cb = cand + (size_t)b * CAP;
  for (int i = tid; i < A; i += 1024) {
    unsigned k = key_of(sc[i]);
    if ((int)(k >> 22) >= T) {
      int pos = atomicAdd(&s_cnt, 1);
      if (pos < CAP)
        cb[pos] = ((unsigned long long)k << 32) | (unsigned)(~i);
    }
  }
  __syncthreads();
  if (tid == 0) cand_cnt[b] = min(s_cnt, CAP);
}

// ---------------- stage 2: bitonic sort candidates, emit top-2000 ----------
__global__ __launch_bounds__(1024) void sort_topk(
    const unsigned long long* __restrict__ cand, const int* __restrict__ cand_cnt,
    int* __restrict__ topk_idx, float* __restrict__ topk_logit) {
  int b = blockIdx.x;
  __shared__ unsigned long long s[CAP];   // 64 KiB
  int n = cand_cnt[b];
  const unsigned long long* cb = cand + (size_t)b * CAP;
  for (int i = threadIdx.x; i < CAP; i += 1024)
    s[i] = (i < n) ? cb[i] : 0ULL;        // pad sorts to the end (descending)
  for (int k = 2; k <= CAP; k <<= 1) {
    for (int j = k >> 1; j > 0; j >>= 1) {
      __syncthreads();
      for (int i = threadIdx.x; i < CAP; i += 1024) {
        int l = i ^ j;
        if (l > i) {
          unsigned long long a = s[i], c2 = s[l];
          bool desc = ((i & k) == 0);
          if (desc ? (a < c2) : (a > c2)) { s[i] = c2; s[l] = a; }
        }
      }
    }
  }
  __syncthreads();
  for (int i = threadIdx.x; i < PRE_NMS; i += 1024) {
    unsigned long long v2 = s[i];
    topk_idx[b * PRE_NMS + i] = (int)(~(unsigned)v2);
    topk_logit[b * PRE_NMS + i] = inv_key((unsigned)(v2 >> 32));
  }
}

// ---------------- stage 3: decode boxes (non-contracted fp32) --------------
__global__ void decode_kernel(const float* __restrict__ deltas,
                              const float* __restrict__ anchors,
                              const int* __restrict__ topk_idx,
                              float* __restrict__ boxes, int A, int B) {
  int t = blockIdx.x * blockDim.x + threadIdx.x;
  if (t >= B * PRE_NMS) return;
  int b = t / PRE_NMS;
  int a = topk_idx[t];
  float4 dl = ((const float4*)deltas)[(size_t)b * A + a];
  float4 an = ((const float4*)anchors)[a];
  const float CLIP = 4.135166556742356f;  // log(1000/16)
  float wa = __fsub_rn(an.z, an.x);
  float ha = __fsub_rn(an.w, an.y);
  float cxa = __fadd_rn(an.x, __fmul_rn(0.5f, wa));
  float cya = __fadd_rn(an.y, __fmul_rn(0.5f, ha));
  float dw = fminf(dl.z, CLIP), dh = fminf(dl.w, CLIP);
  float cx = __fadd_rn(__fmul_rn(dl.x, wa), cxa);
  float cy = __fadd_rn(__fmul_rn(dl.y, ha), cya);
  float w = __fmul_rn((float)exp((double)dw), wa);
  float h = __fmul_rn((float)exp((double)dh), ha);
  float x1 = __fsub_rn(cx, __fmul_rn(0.5f, w));
  float y1 = __fsub_rn(cy, __fmul_rn(0.5f, h));
  float x2 = __fadd_rn(cx, __fmul_rn(0.5f, w));
  float y2 = __fadd_rn(cy, __fmul_rn(0.5f, h));
  x1 = fminf(fmaxf(x1, 0.f), IMGSZ);
  y1 = fminf(fmaxf(y1, 0.f), IMGSZ);
  x2 = fminf(fmaxf(x2, 0.f), IMGSZ);
  y2 = fminf(fmaxf(y2, 0.f), IMGSZ);
  ((float4*)boxes)[t] = make_float4(x1, y1, x2, y2);
}

// ---------------- stage 4: IoU suppression bitmask (j > i) -----------------
__global__ void iou_kernel(const float* __restrict__ boxes,
                           unsigned long long* __restrict__ mask, int B) {
  int t = blockIdx.x * blockDim.x + threadIdx.x;
  if (t >= B * PRE_NMS * NWORDS) return;
  int w = t & (NWORDS - 1);
  int bi = t >> 5;                 // b*PRE_NMS + i
  int i = bi % PRE_NMS;
  int b = bi / PRE_NMS;
  const float4* bb = (const float4*)boxes + (size_t)b * PRE_NMS;
  float4 A4 = bb[i];
  float area_a = __fmul_rn(__fsub_rn(A4.z, A4.x), __fsub_rn(A4.w, A4.y));
  unsigned long long m = 0;
  int j0 = w << 6;
  int jend = min(j0 + 64, PRE_NMS);
  for (int j = max(j0, i + 1); j < jend; ++j) {
    float4 Bb = bb[j];
    float area_b = __fmul_rn(__fsub_rn(Bb.z, Bb.x), __fsub_rn(Bb.w, Bb.y));
    float ltx = fmaxf(A4.x, Bb.x), lty = fmaxf(A4.y, Bb.y);
    float rbx = fminf(A4.z, Bb.z), rby = fminf(A4.w, Bb.w);
    float iw = fmaxf(__fsub_rn(rbx, ltx), 0.f);
    float ih = fmaxf(__fsub_rn(rby, lty), 0.f);
    float inter = __fmul_rn(iw, ih);
    float denom = __fadd_rn(__fsub_rn(__fadd_rn(area_a, area_b), inter), 1e-9f);
    float iou = inter / denom;
    if (iou > IOU_T) m |= 1ULL << (j - j0);
  }
  mask[t] = m;
}

// ---------------- stage 5: sequential greedy scan, one wave per image ------
__global__ __launch_bounds__(64) void nms_scan(
    const unsigned long long* __restrict__ mask,
    unsigned long long* __restrict__ keep, int B) {
  int b = blockIdx.x;
  int lane = threadIdx.x;          // 0..63; lanes 0..31 own keep words
  const unsigned long long* mb = mask + (size_t)b * PRE_NMS * NWORDS;
  unsigned long long kw = ~0ULL;
  for (int c = 0; c < NWORDS; ++c) {
    unsigned long long cur = __shfl(kw, c, 64);   // current chunk's keep word
    int iend = min(64, PRE_NMS - c * 64);
    for (int bb2 = 0; bb2 < iend; ++bb2) {
      int i = c * 64 + bb2;
      unsigned long long row = mb[(size_t)i * NWORDS + (lane & 31)];
      unsigned long long rowc = __shfl(row, c, 64); // off the critical path
      if ((cur >> bb2) & 1) {       // wave-uniform branch
        if (lane < 32) kw &= ~row;
        cur &= ~rowc;               // ALU-only critical chain
      }
    }
  }
  if (lane < 32) keep[b * NWORDS + lane] = kw;
}

// ---------------- stage 6: rank kept boxes, emit [box, sigmoid] ------------
__global__ void write_out(const unsigned long long* __restrict__ keep,
                          const float* __restrict__ boxes,
                          const float* __restrict__ logits,
                          float* __restrict__ out) {
  int b = blockIdx.x;
  __shared__ int pre[NWORDS];
  if (threadIdx.x == 0) {
    int acc = 0;
    for (int w = 0; w < NWORDS; ++w) {
      pre[w] = acc;
      acc += __popcll(keep[b * NWORDS + w]);
    }
  }
  __syncthreads();
  for (int i = threadIdx.x; i < PRE_NMS; i += blockDim.x) {
    unsigned long long w = keep[b * NWORDS + (i >> 6)];
    if ((w >> (i & 63)) & 1) {
      int rank = pre[i >> 6] + __popcll(w & ((1ULL << (i & 63)) - 1ULL));
      if (rank < POST_NMS) {
        float4 bx = ((const float4*)boxes)[(size_t)b * PRE_NMS + i];
        float lg = logits[b * PRE_NMS + i];
        float e = (float)exp(-(double)lg);
        float p = 1.0f / (1.0f + e);
        float* o = out + ((size_t)b * POST_NMS + rank) * 5;
        o[0] = bx.x; o[1] = bx.y; o[2] = bx.z; o[3] = bx.w; o[4] = p;
      }
    }
  }
}

extern "C" void kernel_launch(void* const* d_in, const int* in_sizes, int n_in,
                              void* d_out, int out_size, void* d_ws, size_t ws_size,
                              hipStream_t stream) {
  const float* scores  = (const float*)d_in[0];
  const float* deltas  = (const float*)d_in[1];
  const float* anchors = (const float*)d_in[2];
  int A = in_sizes[2] / 4;          // 159882
  int B = in_sizes[0] / A;          // 16

  char* ws = (char*)d_ws;
  size_t off = 0;
  auto alloc = [&](size_t bytes) {
    void* p = ws + off;
    off += (bytes + 255) & ~(size_t)255;
    return p;
  };
  unsigned long long* cand     = (unsigned long long*)alloc((size_t)B * CAP * 8);
  int*                cand_cnt = (int*)alloc((size_t)B * 4);
  int*                topk_idx = (int*)alloc((size_t)B * PRE_NMS * 4);
  float*              topk_lg  = (float*)alloc((size_t)B * PRE_NMS * 4);
  float*              boxes    = (float*)alloc((size_t)B * PRE_NMS * 16);
  unsigned long long* mask     = (unsigned long long*)alloc((size_t)B * PRE_NMS * NWORDS * 8);
  unsigned long long* keep     = (unsigned long long*)alloc((size_t)B * NWORDS * 8);

  hipMemsetAsync(d_out, 0, (size_t)out_size * 4, stream);

  topk_select<<<B, 1024, 0, stream>>>(scores, A, cand, cand_cnt);
  sort_topk<<<B, 1024, 0, stream>>>(cand, cand_cnt, topk_idx, topk_lg);
  int totalD = B * PRE_NMS;
  decode_kernel<<<(totalD + 255) / 256, 256, 0, stream>>>(deltas, anchors, topk_idx, boxes, A, B);
  int totalI = B * PRE_NMS * NWORDS;
  iou_kernel<<<(totalI + 255) / 256, 256, 0, stream>>>(boxes, mask, B);
  nms_scan<<<B, 64, 0, stream>>>(mask, keep, B);
  write_out<<<B, 256, 0, stream>>>(keep, boxes, topk_lg, (float*)d_out);
}

// Round 2
// 764.519 us; speedup vs baseline: 1.2913x; 1.2913x over previous
//
#include <hip/hip_runtime.h>
#include <math.h>

#define PRE_NMS 2000
#define POST_NMS 1000
#define IOU_T 0.7f
#define IMGSZ 800.0f
#define CAP 6144            // level-1 candidates per image (expected ~3600, max ~5500)
#define SORTN 2048          // level-2 refined candidates (expected ~2003)
#define NBINS 1024
#define NWORDS 32           // ceil(PRE_NMS/64)
#define NSLICE 16           // blocks per image for hist/compact

typedef unsigned long long u64;

__device__ __forceinline__ unsigned key_of(float f) {
    unsigned u = __float_as_uint(f);
    return (u & 0x80000000u) ? ~u : (u | 0x80000000u);
}
__device__ __forceinline__ float inv_key(unsigned k) {
    unsigned u = (k & 0x80000000u) ? (k ^ 0x80000000u) : ~k;
    return __uint_as_float(u);
}

// ---- K1: level-1 histogram (10-bit), 16 slices/image, merge via global atomics
__global__ __launch_bounds__(256) void hist_kernel(
    const float* __restrict__ scores, int A, unsigned* __restrict__ ghist) {
  int b = blockIdx.x, slice = blockIdx.y;
  __shared__ unsigned h[NBINS];
  int tid = threadIdx.x;
  for (int i = tid; i < NBINS; i += 256) h[i] = 0;
  __syncthreads();
  int per = (A + NSLICE - 1) / NSLICE;
  int lo = slice * per, hi = min(lo + per, A);
  const float* sc = scores + (size_t)b * A;
  for (int i = lo + tid; i < hi; i += 256)
    atomicAdd(&h[key_of(sc[i]) >> 22], 1u);
  __syncthreads();
  for (int i = tid; i < NBINS; i += 256)
    if (h[i]) atomicAdd(&ghist[b * NBINS + i], h[i]);
}

// ---- K2: suffix-scan ghist, find level-1 threshold bin T1 ----
__global__ __launch_bounds__(1024) void thresh1_kernel(
    const unsigned* __restrict__ ghist, int* __restrict__ T1) {
  int b = blockIdx.x, tid = threadIdx.x;
  __shared__ unsigned tmp[NBINS];
  __shared__ int s_T;
  unsigned v = ghist[b * NBINS + tid];
  for (int d = 1; d < NBINS; d <<= 1) {
    tmp[tid] = v;
    __syncthreads();
    if (tid + d < NBINS) v += tmp[tid + d];
    __syncthreads();
  }
  tmp[tid] = v;   // count of keys with bin >= tid
  __syncthreads();
  unsigned nextv = (tid < NBINS - 1) ? tmp[tid + 1] : 0u;
  if (v >= PRE_NMS && nextv < PRE_NMS) s_T = tid;
  __syncthreads();
  if (tid == 0) T1[b] = s_T;
}

// ---- K3: compact candidates above T1 (16 slices/image, global atomic count)
__global__ __launch_bounds__(256) void compact_kernel(
    const float* __restrict__ scores, int A, const int* __restrict__ T1,
    u64* __restrict__ cand, int* __restrict__ cand_cnt) {
  int b = blockIdx.x, slice = blockIdx.y;
  int tid = threadIdx.x;
  int T = T1[b];
  int per = (A + NSLICE - 1) / NSLICE;
  int lo = slice * per, hi = min(lo + per, A);
  const float* sc = scores + (size_t)b * A;
  u64* cb = cand + (size_t)b * CAP;
  for (int i = lo + tid; i < hi; i += 256) {
    unsigned k = key_of(sc[i]);
    if ((int)(k >> 22) >= T) {
      int pos = atomicAdd(&cand_cnt[b], 1);
      if (pos < CAP) cb[pos] = ((u64)k << 32) | (unsigned)(~i);
    }
  }
}

// ---- K4: 20-bit threshold refinement + bitonic sort 2048 + emit top-2000 --
__global__ __launch_bounds__(1024) void refine_sort_kernel(
    const u64* __restrict__ cand, const int* __restrict__ cand_cnt,
    const int* __restrict__ T1,
    int* __restrict__ topk_idx, float* __restrict__ topk_logit) {
  int b = blockIdx.x, tid = threadIdx.x;
  int lane = tid & 63;
  __shared__ unsigned h2[NBINS];
  __shared__ unsigned tmp[NBINS];
  __shared__ u64 s[SORTN];
  __shared__ int s_above, s_sel, s_T2;
  int n = min(cand_cnt[b], CAP);
  const u64* cb = cand + (size_t)b * CAP;
  h2[tid] = 0;
  if (tid == 0) { s_above = 0; s_sel = 0; }
  __syncthreads();
  int T1v = T1[b];
  int loc = 0;
  for (int i = tid; i < n; i += 1024) {
    unsigned k = (unsigned)(cb[i] >> 32);
    if ((int)(k >> 22) > T1v) loc++;
    else atomicAdd(&h2[(k >> 12) & 1023], 1u);
  }
  for (int d = 32; d; d >>= 1) loc += __shfl_down(loc, d, 64);
  if (lane == 0 && loc) atomicAdd(&s_above, loc);
  __syncthreads();
  // suffix-scan h2
  unsigned v = h2[tid];
  for (int d = 1; d < NBINS; d <<= 1) {
    tmp[tid] = v;
    __syncthreads();
    if (tid + d < NBINS) v += tmp[tid + d];
    __syncthreads();
  }
  tmp[tid] = v;
  __syncthreads();
  int above = s_above;   // count with 10-bit prefix > T1 (always < 2000)
  unsigned nextv = (tid < NBINS - 1) ? tmp[tid + 1] : 0u;
  if (above + (int)v >= PRE_NMS && above + (int)nextv < PRE_NMS) s_T2 = tid;
  __syncthreads();
  unsigned thresh20 = ((unsigned)T1v << 10) | (unsigned)s_T2;
  // select refined candidates into LDS
  for (int i = tid; i < SORTN; i += 1024) s[i] = 0ULL;
  __syncthreads();
  for (int i = tid; i < n; i += 1024) {
    u64 cv = cb[i];
    if ((unsigned)(cv >> 44) >= thresh20) {
      int pos = atomicAdd(&s_sel, 1);
      if (pos < SORTN) s[pos] = cv;
    }
  }
  __syncthreads();
  // bitonic sort descending (zeros pad to the end)
  for (int k = 2; k <= SORTN; k <<= 1) {
    for (int j = k >> 1; j > 0; j >>= 1) {
      for (int i = tid; i < SORTN; i += 1024) {
        int l = i ^ j;
        if (l > i) {
          u64 a = s[i], c2 = s[l];
          bool desc = ((i & k) == 0);
          if (desc ? (a < c2) : (a > c2)) { s[i] = c2; s[l] = a; }
        }
      }
      __syncthreads();
    }
  }
  for (int i = tid; i < PRE_NMS; i += 1024) {
    u64 v2 = s[i];
    topk_idx[b * PRE_NMS + i] = (int)(~(unsigned)v2);
    topk_logit[b * PRE_NMS + i] = inv_key((unsigned)(v2 >> 32));
  }
}

// ---- decode boxes (non-contracted fp32, matches numpy op-by-op) -----------
__global__ void decode_kernel(const float* __restrict__ deltas,
                              const float* __restrict__ anchors,
                              const int* __restrict__ topk_idx,
                              float* __restrict__ boxes, int A, int B) {
  int t = blockIdx.x * blockDim.x + threadIdx.x;
  if (t >= B * PRE_NMS) return;
  int b = t / PRE_NMS;
  int a = topk_idx[t];
  float4 dl = ((const float4*)deltas)[(size_t)b * A + a];
  float4 an = ((const float4*)anchors)[a];
  const float CLIP = 4.135166556742356f;  // log(1000/16)
  float wa = __fsub_rn(an.z, an.x);
  float ha = __fsub_rn(an.w, an.y);
  float cxa = __fadd_rn(an.x, __fmul_rn(0.5f, wa));
  float cya = __fadd_rn(an.y, __fmul_rn(0.5f, ha));
  float dw = fminf(dl.z, CLIP), dh = fminf(dl.w, CLIP);
  float cx = __fadd_rn(__fmul_rn(dl.x, wa), cxa);
  float cy = __fadd_rn(__fmul_rn(dl.y, ha), cya);
  float w = __fmul_rn((float)exp((double)dw), wa);
  float h = __fmul_rn((float)exp((double)dh), ha);
  float x1 = __fsub_rn(cx, __fmul_rn(0.5f, w));
  float y1 = __fsub_rn(cy, __fmul_rn(0.5f, h));
  float x2 = __fadd_rn(cx, __fmul_rn(0.5f, w));
  float y2 = __fadd_rn(cy, __fmul_rn(0.5f, h));
  x1 = fminf(fmaxf(x1, 0.f), IMGSZ);
  y1 = fminf(fmaxf(y1, 0.f), IMGSZ);
  x2 = fminf(fmaxf(x2, 0.f), IMGSZ);
  y2 = fminf(fmaxf(y2, 0.f), IMGSZ);
  ((float4*)boxes)[t] = make_float4(x1, y1, x2, y2);
}

// ---- IoU suppression bitmask (j > i), one thread per 64-bit word ----------
__global__ void iou_kernel(const float* __restrict__ boxes,
                           u64* __restrict__ mask, int B) {
  int t = blockIdx.x * blockDim.x + threadIdx.x;
  if (t >= B * PRE_NMS * NWORDS) return;
  int w = t & (NWORDS - 1);
  int bi = t >> 5;
  int i = bi % PRE_NMS;
  int b = bi / PRE_NMS;
  const float4* bb = (const float4*)boxes + (size_t)b * PRE_NMS;
  float4 A4 = bb[i];
  float area_a = __fmul_rn(__fsub_rn(A4.z, A4.x), __fsub_rn(A4.w, A4.y));
  u64 m = 0;
  int j0 = w << 6;
  int jend = min(j0 + 64, PRE_NMS);
  for (int j = max(j0, i + 1); j < jend; ++j) {
    float4 Bb = bb[j];
    float area_b = __fmul_rn(__fsub_rn(Bb.z, Bb.x), __fsub_rn(Bb.w, Bb.y));
    float ltx = fmaxf(A4.x, Bb.x), lty = fmaxf(A4.y, Bb.y);
    float rbx = fminf(A4.z, Bb.z), rby = fminf(A4.w, Bb.w);
    float iw = fmaxf(__fsub_rn(rbx, ltx), 0.f);
    float ih = fmaxf(__fsub_rn(rby, lty), 0.f);
    float inter = __fmul_rn(iw, ih);
    float denom = __fadd_rn(__fsub_rn(__fadd_rn(area_a, area_b), inter), 1e-9f);
    float iou = inter / denom;
    if (iou > IOU_T) m |= 1ULL << (j - j0);
  }
  mask[t] = m;
}

// ---- NMS scan: one block/image, LDS-staged chunks, ALU-only serial chain --
// LDS row stride 33 u64 -> bank (2*row)%32 across lanes: 2-way (free).
#define LSTRIDE 33
__global__ __launch_bounds__(1024) void nms_scan(
    const u64* __restrict__ mask, u64* __restrict__ keep_g) {
  int b = blockIdx.x;
  int tid = threadIdx.x;
  int wave = tid >> 6, lane = tid & 63;
  __shared__ u64 buf[2][64 * LSTRIDE];   // 2 x 16.5 KiB
  __shared__ u64 s_keep[NWORDS];
  __shared__ u64 s_cur;
  if (tid < NWORDS) s_keep[tid] = (tid == NWORDS - 1) ? 0xFFFFULL : ~0ULL;
  const u64* mb = mask + (size_t)b * PRE_NMS * NWORDS;
  // each thread owns 2 consecutive u64 of the chunk: linear = 2*tid
  int lin = 2 * tid;
  int r = lin >> 5;        // row within chunk (0..63)
  int w0 = lin & 31;       // word (even)
  // prefetch chunk 0
  uint4 v;
  {
    int grow = r;          // c=0
    if (grow < PRE_NMS) v = *(const uint4*)(mb + (size_t)grow * NWORDS + w0);
    else v = make_uint4(0, 0, 0, 0);
  }
  {
    u64 a = ((u64)v.y << 32) | v.x;
    u64 c2 = ((u64)v.w << 32) | v.z;
    buf[0][r * LSTRIDE + w0] = a;
    buf[0][r * LSTRIDE + w0 + 1] = c2;
  }
  for (int c = 0; c < NWORDS; ++c) {
    int p = c & 1;
    // issue prefetch of chunk c+1 (off critical path)
    if (c + 1 < NWORDS) {
      int grow = (c + 1) * 64 + r;
      if (grow < PRE_NMS) v = *(const uint4*)(mb + (size_t)grow * NWORDS + w0);
      else v = make_uint4(0, 0, 0, 0);
    }
    __syncthreads();   // buf[p] writes visible; prior-iter reads of buf[p^1] done
    // store prefetched chunk into the other buffer
    if (c + 1 < NWORDS) {
      u64 a = ((u64)v.y << 32) | v.x;
      u64 c2 = ((u64)v.w << 32) | v.z;
      buf[p ^ 1][r * LSTRIDE + w0] = a;
      buf[p ^ 1][r * LSTRIDE + w0 + 1] = c2;
    }
    // wave 0: serial diagonal scan (ALU-only dependency chain)
    if (wave == 0) {
      u64 diag = buf[p][lane * LSTRIDE + c];   // row `lane`, word c
      u64 cur = s_keep[c];
      #pragma unroll
      for (int bb = 0; bb < 64; ++bb) {
        u64 rowc = __shfl(diag, bb, 64);       // off the critical path
        if ((cur >> bb) & 1) cur &= ~rowc;
      }
      if (lane == 0) { s_keep[c] = cur; s_cur = cur; }
    }
    __syncthreads();
    // parallel suppression sweep: wave v owns words 2v, 2v+1 (only w > c)
    {
      u64 cur = s_cur;
      int wA = wave * 2, wB = wave * 2 + 1;
      bool doA = wA > c, doB = wB > c;
      u64 vA = (doA && ((cur >> lane) & 1)) ? buf[p][lane * LSTRIDE + wA] : 0ULL;
      u64 vB = (doB && ((cur >> lane) & 1)) ? buf[p][lane * LSTRIDE + wB] : 0ULL;
      #pragma unroll
      for (int d = 1; d < 64; d <<= 1) {
        vA |= __shfl_xor(vA, d, 64);
        vB |= __shfl_xor(vB, d, 64);
      }
      if (lane == 0) {
        if (doA) s_keep[wA] &= ~vA;
        if (doB) s_keep[wB] &= ~vB;
      }
    }
  }
  __syncthreads();
  if (tid < NWORDS) keep_g[b * NWORDS + tid] = s_keep[tid];
}

// ---- rank kept boxes, emit [box, sigmoid] ---------------------------------
__global__ void write_out(const u64* __restrict__ keep,
                          const float* __restrict__ boxes,
                          const float* __restrict__ logits,
                          float* __restrict__ out) {
  int b = blockIdx.x;
  __shared__ int pre[NWORDS];
  if (threadIdx.x == 0) {
    int acc = 0;
    for (int w = 0; w < NWORDS; ++w) {
      pre[w] = acc;
      acc += __popcll(keep[b * NWORDS + w]);
    }
  }
  __syncthreads();
  for (int i = threadIdx.x; i < PRE_NMS; i += blockDim.x) {
    u64 w = keep[b * NWORDS + (i >> 6)];
    if ((w >> (i & 63)) & 1) {
      int rank = pre[i >> 6] + __popcll(w & ((1ULL << (i & 63)) - 1ULL));
      if (rank < POST_NMS) {
        float4 bx = ((const float4*)boxes)[(size_t)b * PRE_NMS + i];
        float lg = logits[b * PRE_NMS + i];
        float e = (float)exp(-(double)lg);
        float p = 1.0f / (1.0f + e);
        float* o = out + ((size_t)b * POST_NMS + rank) * 5;
        o[0] = bx.x; o[1] = bx.y; o[2] = bx.z; o[3] = bx.w; o[4] = p;
      }
    }
  }
}

extern "C" void kernel_launch(void* const* d_in, const int* in_sizes, int n_in,
                              void* d_out, int out_size, void* d_ws, size_t ws_size,
                              hipStream_t stream) {
  const float* scores  = (const float*)d_in[0];
  const float* deltas  = (const float*)d_in[1];
  const float* anchors = (const float*)d_in[2];
  int A = in_sizes[2] / 4;          // 159882
  int B = in_sizes[0] / A;          // 16

  char* ws = (char*)d_ws;
  size_t off = 0;
  auto alloc = [&](size_t bytes) {
    void* p = ws + off;
    off += (bytes + 255) & ~(size_t)255;
    return p;
  };
  // zeroed region (one memset): ghist | ghist2(unused slot kept for align) | cand_cnt
  unsigned* ghist    = (unsigned*)alloc((size_t)B * NBINS * 4);   // 64 KiB
  int*      cand_cnt = (int*)alloc((size_t)B * 4);
  size_t zero_bytes = off;
  int*      T1       = (int*)alloc((size_t)B * 4);
  u64*      cand     = (u64*)alloc((size_t)B * CAP * 8);
  int*      topk_idx = (int*)alloc((size_t)B * PRE_NMS * 4);
  float*    topk_lg  = (float*)alloc((size_t)B * PRE_NMS * 4);
  float*    boxes    = (float*)alloc((size_t)B * PRE_NMS * 16);
  u64*      mask     = (u64*)alloc((size_t)B * PRE_NMS * NWORDS * 8);
  u64*      keep     = (u64*)alloc((size_t)B * NWORDS * 8);

  hipMemsetAsync(d_out, 0, (size_t)out_size * 4, stream);
  hipMemsetAsync(ws, 0, zero_bytes, stream);

  hist_kernel<<<dim3(B, NSLICE), 256, 0, stream>>>(scores, A, ghist);
  thresh1_kernel<<<B, 1024, 0, stream>>>(ghist, T1);
  compact_kernel<<<dim3(B, NSLICE), 256, 0, stream>>>(scores, A, T1, cand, cand_cnt);
  refine_sort_kernel<<<B, 1024, 0, stream>>>(cand, cand_cnt, T1, topk_idx, topk_lg);
  int totalD = B * PRE_NMS;
  decode_kernel<<<(totalD + 255) / 256, 256, 0, stream>>>(deltas, anchors, topk_idx, boxes, A, B);
  int totalI = B * PRE_NMS * NWORDS;
  iou_kernel<<<(totalI + 255) / 256, 256, 0, stream>>>(boxes, mask, B);
  nms_scan<<<B, 1024, 0, stream>>>(mask, keep);
  write_out<<<B, 256, 0, stream>>>(keep, boxes, topk_lg, (float*)d_out);
}

// Round 3
// 423.015 us; speedup vs baseline: 2.3337x; 1.8073x over previous
//
#include <hip/hip_runtime.h>
#include <math.h>

#define PRE_NMS 2000
#define POST_NMS 1000
#define IOU_T 0.7f
#define IMGSZ 800.0f
#define CAP 6144            // level-1 candidates per image (expected ~3600)
#define SORTN 2048          // level-2 refined candidates (expected ~2003)
#define NBINS 1024
#define NWORDS 32           // ceil(PRE_NMS/64)
#define NSLICE 16           // blocks per image for hist/compact

typedef unsigned long long u64;

__device__ __forceinline__ unsigned key_of(float f) {
    unsigned u = __float_as_uint(f);
    return (u & 0x80000000u) ? ~u : (u | 0x80000000u);
}
__device__ __forceinline__ float inv_key(unsigned k) {
    unsigned u = (k & 0x80000000u) ? (k ^ 0x80000000u) : ~k;
    return __uint_as_float(u);
}

// ---- K1: level-1 histogram (10-bit), 16 slices/image, merge via global atomics
__global__ __launch_bounds__(256) void hist_kernel(
    const float* __restrict__ scores, int A, unsigned* __restrict__ ghist) {
  int b = blockIdx.x, slice = blockIdx.y;
  __shared__ unsigned h[NBINS];
  int tid = threadIdx.x;
  for (int i = tid; i < NBINS; i += 256) h[i] = 0;
  __syncthreads();
  int per = (A + NSLICE - 1) / NSLICE;
  int lo = slice * per, hi = min(lo + per, A);
  const float* sc = scores + (size_t)b * A;
  for (int i = lo + tid; i < hi; i += 256)
    atomicAdd(&h[key_of(sc[i]) >> 22], 1u);
  __syncthreads();
  for (int i = tid; i < NBINS; i += 256)
    if (h[i]) atomicAdd(&ghist[b * NBINS + i], h[i]);
}

// ---- K2: suffix-scan ghist, find level-1 threshold bin T1 ----
__global__ __launch_bounds__(1024) void thresh1_kernel(
    const unsigned* __restrict__ ghist, int* __restrict__ T1) {
  int b = blockIdx.x, tid = threadIdx.x;
  __shared__ unsigned tmp[NBINS];
  __shared__ int s_T;
  unsigned v = ghist[b * NBINS + tid];
  for (int d = 1; d < NBINS; d <<= 1) {
    tmp[tid] = v;
    __syncthreads();
    if (tid + d < NBINS) v += tmp[tid + d];
    __syncthreads();
  }
  tmp[tid] = v;   // count of keys with bin >= tid
  __syncthreads();
  unsigned nextv = (tid < NBINS - 1) ? tmp[tid + 1] : 0u;
  if (v >= PRE_NMS && nextv < PRE_NMS) s_T = tid;
  __syncthreads();
  if (tid == 0) T1[b] = s_T;
}

// ---- K3: compact candidates above T1 -------------------------------------
// Two-phase: block-local count + single atomic range-reserve per block, then
// re-scan (L2-resident slice) and scatter at base+prefix. 256 global atomics
// total vs ~57k same-address ones before (which serialized at ~100ns each).
__global__ __launch_bounds__(256) void compact_kernel(
    const float* __restrict__ scores, int A, const int* __restrict__ T1,
    u64* __restrict__ cand, int* __restrict__ cand_cnt) {
  int b = blockIdx.x, slice = blockIdx.y;
  int tid = threadIdx.x;
  int lane = tid & 63, wave = tid >> 6;
  int T = T1[b];
  int per = (A + NSLICE - 1) / NSLICE;
  int lo = slice * per, hi = min(lo + per, A);
  const float* sc = scores + (size_t)b * A;
  // phase 1: count hits per thread
  int cnt = 0;
  for (int i = lo + tid; i < hi; i += 256)
    cnt += ((int)(key_of(sc[i]) >> 22) >= T);
  // inclusive wave prefix
  int pfx = cnt;
  #pragma unroll
  for (int d = 1; d < 64; d <<= 1) {
    int t2 = __shfl_up(pfx, d, 64);
    if (lane >= d) pfx += t2;
  }
  __shared__ int s_wt[4];
  __shared__ int s_base;
  if (lane == 63) s_wt[wave] = pfx;
  __syncthreads();
  if (tid == 0) {
    int tot = s_wt[0] + s_wt[1] + s_wt[2] + s_wt[3];
    int acc = 0;
    #pragma unroll
    for (int w2 = 0; w2 < 4; ++w2) { int t3 = s_wt[w2]; s_wt[w2] = acc; acc += t3; }
    s_base = atomicAdd(&cand_cnt[b], tot);
  }
  __syncthreads();
  int my_off = s_base + s_wt[wave] + (pfx - cnt);  // exclusive thread offset
  u64* cb = cand + (size_t)b * CAP;
  // phase 2: re-scan (slice is L2-hot) and scatter
  for (int i = lo + tid; i < hi; i += 256) {
    unsigned k = key_of(sc[i]);
    if ((int)(k >> 22) >= T) {
      if (my_off < CAP) cb[my_off] = ((u64)k << 32) | (unsigned)(~i);
      my_off++;
    }
  }
}

// ---- K4: 20-bit threshold refinement + bitonic sort 2048 + emit top-2000 --
__global__ __launch_bounds__(1024) void refine_sort_kernel(
    const u64* __restrict__ cand, const int* __restrict__ cand_cnt,
    const int* __restrict__ T1,
    int* __restrict__ topk_idx, float* __restrict__ topk_logit) {
  int b = blockIdx.x, tid = threadIdx.x;
  int lane = tid & 63;
  __shared__ unsigned h2[NBINS];
  __shared__ unsigned tmp[NBINS];
  __shared__ u64 s[SORTN];
  __shared__ int s_above, s_sel, s_T2;
  int n = min(cand_cnt[b], CAP);
  const u64* cb = cand + (size_t)b * CAP;
  h2[tid] = 0;
  if (tid == 0) { s_above = 0; s_sel = 0; }
  __syncthreads();
  int T1v = T1[b];
  int loc = 0;
  for (int i = tid; i < n; i += 1024) {
    unsigned k = (unsigned)(cb[i] >> 32);
    if ((int)(k >> 22) > T1v) loc++;
    else atomicAdd(&h2[(k >> 12) & 1023], 1u);
  }
  for (int d = 32; d; d >>= 1) loc += __shfl_down(loc, d, 64);
  if (lane == 0 && loc) atomicAdd(&s_above, loc);
  __syncthreads();
  // suffix-scan h2
  unsigned v = h2[tid];
  for (int d = 1; d < NBINS; d <<= 1) {
    tmp[tid] = v;
    __syncthreads();
    if (tid + d < NBINS) v += tmp[tid + d];
    __syncthreads();
  }
  tmp[tid] = v;
  __syncthreads();
  int above = s_above;   // count with 10-bit prefix > T1 (always < 2000)
  unsigned nextv = (tid < NBINS - 1) ? tmp[tid + 1] : 0u;
  if (above + (int)v >= PRE_NMS && above + (int)nextv < PRE_NMS) s_T2 = tid;
  __syncthreads();
  unsigned thresh20 = ((unsigned)T1v << 10) | (unsigned)s_T2;
  // select refined candidates into LDS
  for (int i = tid; i < SORTN; i += 1024) s[i] = 0ULL;
  __syncthreads();
  for (int i = tid; i < n; i += 1024) {
    u64 cv = cb[i];
    if ((unsigned)(cv >> 44) >= thresh20) {
      int pos = atomicAdd(&s_sel, 1);
      if (pos < SORTN) s[pos] = cv;
    }
  }
  __syncthreads();
  // bitonic sort descending (zeros pad to the end)
  for (int k = 2; k <= SORTN; k <<= 1) {
    for (int j = k >> 1; j > 0; j >>= 1) {
      for (int i = tid; i < SORTN; i += 1024) {
        int l = i ^ j;
        if (l > i) {
          u64 a = s[i], c2 = s[l];
          bool desc = ((i & k) == 0);
          if (desc ? (a < c2) : (a > c2)) { s[i] = c2; s[l] = a; }
        }
      }
      __syncthreads();
    }
  }
  for (int i = tid; i < PRE_NMS; i += 1024) {
    u64 v2 = s[i];
    topk_idx[b * PRE_NMS + i] = (int)(~(unsigned)v2);
    topk_logit[b * PRE_NMS + i] = inv_key((unsigned)(v2 >> 32));
  }
}

// ---- decode boxes (non-contracted fp32, matches numpy op-by-op) -----------
__global__ void decode_kernel(const float* __restrict__ deltas,
                              const float* __restrict__ anchors,
                              const int* __restrict__ topk_idx,
                              float* __restrict__ boxes, int A, int B) {
  int t = blockIdx.x * blockDim.x + threadIdx.x;
  if (t >= B * PRE_NMS) return;
  int b = t / PRE_NMS;
  int a = topk_idx[t];
  float4 dl = ((const float4*)deltas)[(size_t)b * A + a];
  float4 an = ((const float4*)anchors)[a];
  const float CLIP = 4.135166556742356f;  // log(1000/16)
  float wa = __fsub_rn(an.z, an.x);
  float ha = __fsub_rn(an.w, an.y);
  float cxa = __fadd_rn(an.x, __fmul_rn(0.5f, wa));
  float cya = __fadd_rn(an.y, __fmul_rn(0.5f, ha));
  float dw = fminf(dl.z, CLIP), dh = fminf(dl.w, CLIP);
  float cx = __fadd_rn(__fmul_rn(dl.x, wa), cxa);
  float cy = __fadd_rn(__fmul_rn(dl.y, ha), cya);
  float w = __fmul_rn((float)exp((double)dw), wa);
  float h = __fmul_rn((float)exp((double)dh), ha);
  float x1 = __fsub_rn(cx, __fmul_rn(0.5f, w));
  float y1 = __fsub_rn(cy, __fmul_rn(0.5f, h));
  float x2 = __fadd_rn(cx, __fmul_rn(0.5f, w));
  float y2 = __fadd_rn(cy, __fmul_rn(0.5f, h));
  x1 = fminf(fmaxf(x1, 0.f), IMGSZ);
  y1 = fminf(fmaxf(y1, 0.f), IMGSZ);
  x2 = fminf(fmaxf(x2, 0.f), IMGSZ);
  y2 = fminf(fmaxf(y2, 0.f), IMGSZ);
  ((float4*)boxes)[t] = make_float4(x1, y1, x2, y2);
}

// ---- IoU suppression bitmask (j > i), one thread per 64-bit word ----------
__global__ void iou_kernel(const float* __restrict__ boxes,
                           u64* __restrict__ mask, int B) {
  int t = blockIdx.x * blockDim.x + threadIdx.x;
  if (t >= B * PRE_NMS * NWORDS) return;
  int w = t & (NWORDS - 1);
  int bi = t >> 5;
  int i = bi % PRE_NMS;
  int b = bi / PRE_NMS;
  const float4* bb = (const float4*)boxes + (size_t)b * PRE_NMS;
  float4 A4 = bb[i];
  float area_a = __fmul_rn(__fsub_rn(A4.z, A4.x), __fsub_rn(A4.w, A4.y));
  u64 m = 0;
  int j0 = w << 6;
  int jend = min(j0 + 64, PRE_NMS);
  for (int j = max(j0, i + 1); j < jend; ++j) {
    float4 Bb = bb[j];
    float area_b = __fmul_rn(__fsub_rn(Bb.z, Bb.x), __fsub_rn(Bb.w, Bb.y));
    float ltx = fmaxf(A4.x, Bb.x), lty = fmaxf(A4.y, Bb.y);
    float rbx = fminf(A4.z, Bb.z), rby = fminf(A4.w, Bb.w);
    float iw = fmaxf(__fsub_rn(rbx, ltx), 0.f);
    float ih = fmaxf(__fsub_rn(rby, lty), 0.f);
    float inter = __fmul_rn(iw, ih);
    float denom = __fadd_rn(__fsub_rn(__fadd_rn(area_a, area_b), inter), 1e-9f);
    float iou = inter / denom;
    if (iou > IOU_T) m |= 1ULL << (j - j0);
  }
  mask[t] = m;
}

// ---- NMS scan: one block/image, LDS-staged chunks, ALU-only serial chain --
// LDS row stride 33 u64 -> bank (2*row)%32 across lanes: 2-way (free).
#define LSTRIDE 33
__global__ __launch_bounds__(1024) void nms_scan(
    const u64* __restrict__ mask, u64* __restrict__ keep_g) {
  int b = blockIdx.x;
  int tid = threadIdx.x;
  int wave = tid >> 6, lane = tid & 63;
  __shared__ u64 buf[2][64 * LSTRIDE];   // 2 x 16.5 KiB
  __shared__ u64 s_keep[NWORDS];
  __shared__ u64 s_cur;
  if (tid < NWORDS) s_keep[tid] = (tid == NWORDS - 1) ? 0xFFFFULL : ~0ULL;
  const u64* mb = mask + (size_t)b * PRE_NMS * NWORDS;
  // each thread owns 2 consecutive u64 of the chunk: linear = 2*tid
  int lin = 2 * tid;
  int r = lin >> 5;        // row within chunk (0..63)
  int w0 = lin & 31;       // word (even)
  // prefetch chunk 0
  uint4 v;
  {
    int grow = r;          // c=0
    if (grow < PRE_NMS) v = *(const uint4*)(mb + (size_t)grow * NWORDS + w0);
    else v = make_uint4(0, 0, 0, 0);
  }
  {
    u64 a = ((u64)v.y << 32) | v.x;
    u64 c2 = ((u64)v.w << 32) | v.z;
    buf[0][r * LSTRIDE + w0] = a;
    buf[0][r * LSTRIDE + w0 + 1] = c2;
  }
  for (int c = 0; c < NWORDS; ++c) {
    int p = c & 1;
    // issue prefetch of chunk c+1 (off critical path)
    if (c + 1 < NWORDS) {
      int grow = (c + 1) * 64 + r;
      if (grow < PRE_NMS) v = *(const uint4*)(mb + (size_t)grow * NWORDS + w0);
      else v = make_uint4(0, 0, 0, 0);
    }
    __syncthreads();   // buf[p] writes visible; prior-iter reads of buf[p^1] done
    // store prefetched chunk into the other buffer
    if (c + 1 < NWORDS) {
      u64 a = ((u64)v.y << 32) | v.x;
      u64 c2 = ((u64)v.w << 32) | v.z;
      buf[p ^ 1][r * LSTRIDE + w0] = a;
      buf[p ^ 1][r * LSTRIDE + w0 + 1] = c2;
    }
    // wave 0: serial diagonal scan (ALU-only dependency chain)
    if (wave == 0) {
      u64 diag = buf[p][lane * LSTRIDE + c];   // row `lane`, word c
      u64 cur = s_keep[c];
      #pragma unroll
      for (int bb = 0; bb < 64; ++bb) {
        u64 rowc = __shfl(diag, bb, 64);       // off the critical path
        if ((cur >> bb) & 1) cur &= ~rowc;
      }
      if (lane == 0) { s_keep[c] = cur; s_cur = cur; }
    }
    __syncthreads();
    // parallel suppression sweep: wave v owns words 2v, 2v+1 (only w > c)
    {
      u64 cur = s_cur;
      int wA = wave * 2, wB = wave * 2 + 1;
      bool doA = wA > c, doB = wB > c;
      u64 vA = (doA && ((cur >> lane) & 1)) ? buf[p][lane * LSTRIDE + wA] : 0ULL;
      u64 vB = (doB && ((cur >> lane) & 1)) ? buf[p][lane * LSTRIDE + wB] : 0ULL;
      #pragma unroll
      for (int d = 1; d < 64; d <<= 1) {
        vA |= __shfl_xor(vA, d, 64);
        vB |= __shfl_xor(vB, d, 64);
      }
      if (lane == 0) {
        if (doA) s_keep[wA] &= ~vA;
        if (doB) s_keep[wB] &= ~vB;
      }
    }
  }
  __syncthreads();
  if (tid < NWORDS) keep_g[b * NWORDS + tid] = s_keep[tid];
}

// ---- rank kept boxes, emit [box, sigmoid] ---------------------------------
__global__ void write_out(const u64* __restrict__ keep,
                          const float* __restrict__ boxes,
                          const float* __restrict__ logits,
                          float* __restrict__ out) {
  int b = blockIdx.x;
  __shared__ int pre[NWORDS];
  if (threadIdx.x == 0) {
    int acc = 0;
    for (int w = 0; w < NWORDS; ++w) {
      pre[w] = acc;
      acc += __popcll(keep[b * NWORDS + w]);
    }
  }
  __syncthreads();
  for (int i = threadIdx.x; i < PRE_NMS; i += blockDim.x) {
    u64 w = keep[b * NWORDS + (i >> 6)];
    if ((w >> (i & 63)) & 1) {
      int rank = pre[i >> 6] + __popcll(w & ((1ULL << (i & 63)) - 1ULL));
      if (rank < POST_NMS) {
        float4 bx = ((const float4*)boxes)[(size_t)b * PRE_NMS + i];
        float lg = logits[b * PRE_NMS + i];
        float e = (float)exp(-(double)lg);
        float p = 1.0f / (1.0f + e);
        float* o = out + ((size_t)b * POST_NMS + rank) * 5;
        o[0] = bx.x; o[1] = bx.y; o[2] = bx.z; o[3] = bx.w; o[4] = p;
      }
    }
  }
}

extern "C" void kernel_launch(void* const* d_in, const int* in_sizes, int n_in,
                              void* d_out, int out_size, void* d_ws, size_t ws_size,
                              hipStream_t stream) {
  const float* scores  = (const float*)d_in[0];
  const float* deltas  = (const float*)d_in[1];
  const float* anchors = (const float*)d_in[2];
  int A = in_sizes[2] / 4;          // 159882
  int B = in_sizes[0] / A;          // 16

  char* ws = (char*)d_ws;
  size_t off = 0;
  auto alloc = [&](size_t bytes) {
    void* p = ws + off;
    off += (bytes + 255) & ~(size_t)255;
    return p;
  };
  // zeroed region (one memset): ghist | cand_cnt
  unsigned* ghist    = (unsigned*)alloc((size_t)B * NBINS * 4);   // 64 KiB
  int*      cand_cnt = (int*)alloc((size_t)B * 4);
  size_t zero_bytes = off;
  int*      T1       = (int*)alloc((size_t)B * 4);
  u64*      cand     = (u64*)alloc((size_t)B * CAP * 8);
  int*      topk_idx = (int*)alloc((size_t)B * PRE_NMS * 4);
  float*    topk_lg  = (float*)alloc((size_t)B * PRE_NMS * 4);
  float*    boxes    = (float*)alloc((size_t)B * PRE_NMS * 16);
  u64*      mask     = (u64*)alloc((size_t)B * PRE_NMS * NWORDS * 8);
  u64*      keep     = (u64*)alloc((size_t)B * NWORDS * 8);

  hipMemsetAsync(d_out, 0, (size_t)out_size * 4, stream);
  hipMemsetAsync(ws, 0, zero_bytes, stream);

  hist_kernel<<<dim3(B, NSLICE), 256, 0, stream>>>(scores, A, ghist);
  thresh1_kernel<<<B, 1024, 0, stream>>>(ghist, T1);
  compact_kernel<<<dim3(B, NSLICE), 256, 0, stream>>>(scores, A, T1, cand, cand_cnt);
  refine_sort_kernel<<<B, 1024, 0, stream>>>(cand, cand_cnt, T1, topk_idx, topk_lg);
  int totalD = B * PRE_NMS;
  decode_kernel<<<(totalD + 255) / 256, 256, 0, stream>>>(deltas, anchors, topk_idx, boxes, A, B);
  int totalI = B * PRE_NMS * NWORDS;
  iou_kernel<<<(totalI + 255) / 256, 256, 0, stream>>>(boxes, mask, B);
  nms_scan<<<B, 1024, 0, stream>>>(mask, keep);
  write_out<<<B, 256, 0, stream>>>(keep, boxes, topk_lg, (float*)d_out);
}

// Round 4
// 390.927 us; speedup vs baseline: 2.5253x; 1.0821x over previous
//
#include <hip/hip_runtime.h>
#include <math.h>

#define PRE_NMS 2000
#define POST_NMS 1000
#define IOU_T 0.7f
#define IMGSZ 800.0f
#define CAP 6144            // level-1 candidates per image (expected ~3600)
#define SORTN 2048          // level-2 refined candidates (expected ~2003)
#define NBINS 1024
#define NWORDS 32           // ceil(PRE_NMS/64)
#define NSLICE 16           // blocks per image for hist/compact

typedef unsigned long long u64;

__device__ __forceinline__ unsigned key_of(float f) {
    unsigned u = __float_as_uint(f);
    return (u & 0x80000000u) ? ~u : (u | 0x80000000u);
}
__device__ __forceinline__ float inv_key(unsigned k) {
    unsigned u = (k & 0x80000000u) ? (k ^ 0x80000000u) : ~k;
    return __uint_as_float(u);
}

// ---- K1: level-1 histogram (10-bit), 16 slices/image, merge via global atomics
__global__ __launch_bounds__(256) void hist_kernel(
    const float* __restrict__ scores, int A, unsigned* __restrict__ ghist) {
  int b = blockIdx.x, slice = blockIdx.y;
  __shared__ unsigned h[NBINS];
  int tid = threadIdx.x;
  for (int i = tid; i < NBINS; i += 256) h[i] = 0;
  __syncthreads();
  int per = (A + NSLICE - 1) / NSLICE;
  int lo = slice * per, hi = min(lo + per, A);
  const float* sc = scores + (size_t)b * A;
  for (int i = lo + tid; i < hi; i += 256)
    atomicAdd(&h[key_of(sc[i]) >> 22], 1u);
  __syncthreads();
  for (int i = tid; i < NBINS; i += 256)
    if (h[i]) atomicAdd(&ghist[b * NBINS + i], h[i]);
}

// ---- K2: suffix-scan ghist, find level-1 threshold bin T1 ----
__global__ __launch_bounds__(1024) void thresh1_kernel(
    const unsigned* __restrict__ ghist, int* __restrict__ T1) {
  int b = blockIdx.x, tid = threadIdx.x;
  __shared__ unsigned tmp[NBINS];
  __shared__ int s_T;
  unsigned v = ghist[b * NBINS + tid];
  for (int d = 1; d < NBINS; d <<= 1) {
    tmp[tid] = v;
    __syncthreads();
    if (tid + d < NBINS) v += tmp[tid + d];
    __syncthreads();
  }
  tmp[tid] = v;   // count of keys with bin >= tid
  __syncthreads();
  unsigned nextv = (tid < NBINS - 1) ? tmp[tid + 1] : 0u;
  if (v >= PRE_NMS && nextv < PRE_NMS) s_T = tid;
  __syncthreads();
  if (tid == 0) T1[b] = s_T;
}

// ---- K3: compact candidates above T1 (two-phase, 1 atomic/block) ----------
__global__ __launch_bounds__(256) void compact_kernel(
    const float* __restrict__ scores, int A, const int* __restrict__ T1,
    u64* __restrict__ cand, int* __restrict__ cand_cnt) {
  int b = blockIdx.x, slice = blockIdx.y;
  int tid = threadIdx.x;
  int lane = tid & 63, wave = tid >> 6;
  int T = T1[b];
  int per = (A + NSLICE - 1) / NSLICE;
  int lo = slice * per, hi = min(lo + per, A);
  const float* sc = scores + (size_t)b * A;
  int cnt = 0;
  for (int i = lo + tid; i < hi; i += 256)
    cnt += ((int)(key_of(sc[i]) >> 22) >= T);
  int pfx = cnt;
  #pragma unroll
  for (int d = 1; d < 64; d <<= 1) {
    int t2 = __shfl_up(pfx, d, 64);
    if (lane >= d) pfx += t2;
  }
  __shared__ int s_wt[4];
  __shared__ int s_base;
  if (lane == 63) s_wt[wave] = pfx;
  __syncthreads();
  if (tid == 0) {
    int tot = s_wt[0] + s_wt[1] + s_wt[2] + s_wt[3];
    int acc = 0;
    #pragma unroll
    for (int w2 = 0; w2 < 4; ++w2) { int t3 = s_wt[w2]; s_wt[w2] = acc; acc += t3; }
    s_base = atomicAdd(&cand_cnt[b], tot);
  }
  __syncthreads();
  int my_off = s_base + s_wt[wave] + (pfx - cnt);
  u64* cb = cand + (size_t)b * CAP;
  for (int i = lo + tid; i < hi; i += 256) {
    unsigned k = key_of(sc[i]);
    if ((int)(k >> 22) >= T) {
      if (my_off < CAP) cb[my_off] = ((u64)k << 32) | (unsigned)(~i);
      my_off++;
    }
  }
}

// ---- K4: 20-bit threshold refinement + bitonic sort 2048 + emit top-2000 --
__global__ __launch_bounds__(1024) void refine_sort_kernel(
    const u64* __restrict__ cand, const int* __restrict__ cand_cnt,
    const int* __restrict__ T1,
    int* __restrict__ topk_idx, float* __restrict__ topk_logit) {
  int b = blockIdx.x, tid = threadIdx.x;
  int lane = tid & 63;
  __shared__ unsigned h2[NBINS];
  __shared__ unsigned tmp[NBINS];
  __shared__ u64 s[SORTN];
  __shared__ int s_above, s_sel, s_T2;
  int n = min(cand_cnt[b], CAP);
  const u64* cb = cand + (size_t)b * CAP;
  h2[tid] = 0;
  if (tid == 0) { s_above = 0; s_sel = 0; }
  __syncthreads();
  int T1v = T1[b];
  int loc = 0;
  for (int i = tid; i < n; i += 1024) {
    unsigned k = (unsigned)(cb[i] >> 32);
    if ((int)(k >> 22) > T1v) loc++;
    else atomicAdd(&h2[(k >> 12) & 1023], 1u);
  }
  for (int d = 32; d; d >>= 1) loc += __shfl_down(loc, d, 64);
  if (lane == 0 && loc) atomicAdd(&s_above, loc);
  __syncthreads();
  unsigned v = h2[tid];
  for (int d = 1; d < NBINS; d <<= 1) {
    tmp[tid] = v;
    __syncthreads();
    if (tid + d < NBINS) v += tmp[tid + d];
    __syncthreads();
  }
  tmp[tid] = v;
  __syncthreads();
  int above = s_above;
  unsigned nextv = (tid < NBINS - 1) ? tmp[tid + 1] : 0u;
  if (above + (int)v >= PRE_NMS && above + (int)nextv < PRE_NMS) s_T2 = tid;
  __syncthreads();
  unsigned thresh20 = ((unsigned)T1v << 10) | (unsigned)s_T2;
  for (int i = tid; i < SORTN; i += 1024) s[i] = 0ULL;
  __syncthreads();
  for (int i = tid; i < n; i += 1024) {
    u64 cv = cb[i];
    if ((unsigned)(cv >> 44) >= thresh20) {
      int pos = atomicAdd(&s_sel, 1);
      if (pos < SORTN) s[pos] = cv;
    }
  }
  __syncthreads();
  for (int k = 2; k <= SORTN; k <<= 1) {
    for (int j = k >> 1; j > 0; j >>= 1) {
      for (int i = tid; i < SORTN; i += 1024) {
        int l = i ^ j;
        if (l > i) {
          u64 a = s[i], c2 = s[l];
          bool desc = ((i & k) == 0);
          if (desc ? (a < c2) : (a > c2)) { s[i] = c2; s[l] = a; }
        }
      }
      __syncthreads();
    }
  }
  for (int i = tid; i < PRE_NMS; i += 1024) {
    u64 v2 = s[i];
    topk_idx[b * PRE_NMS + i] = (int)(~(unsigned)v2);
    topk_logit[b * PRE_NMS + i] = inv_key((unsigned)(v2 >> 32));
  }
}

// ---- decode boxes (non-contracted fp32, matches numpy op-by-op) -----------
__global__ void decode_kernel(const float* __restrict__ deltas,
                              const float* __restrict__ anchors,
                              const int* __restrict__ topk_idx,
                              float* __restrict__ boxes, int A, int B) {
  int t = blockIdx.x * blockDim.x + threadIdx.x;
  if (t >= B * PRE_NMS) return;
  int b = t / PRE_NMS;
  int a = topk_idx[t];
  float4 dl = ((const float4*)deltas)[(size_t)b * A + a];
  float4 an = ((const float4*)anchors)[a];
  const float CLIP = 4.135166556742356f;  // log(1000/16)
  float wa = __fsub_rn(an.z, an.x);
  float ha = __fsub_rn(an.w, an.y);
  float cxa = __fadd_rn(an.x, __fmul_rn(0.5f, wa));
  float cya = __fadd_rn(an.y, __fmul_rn(0.5f, ha));
  float dw = fminf(dl.z, CLIP), dh = fminf(dl.w, CLIP);
  float cx = __fadd_rn(__fmul_rn(dl.x, wa), cxa);
  float cy = __fadd_rn(__fmul_rn(dl.y, ha), cya);
  float w = __fmul_rn((float)exp((double)dw), wa);
  float h = __fmul_rn((float)exp((double)dh), ha);
  float x1 = __fsub_rn(cx, __fmul_rn(0.5f, w));
  float y1 = __fsub_rn(cy, __fmul_rn(0.5f, h));
  float x2 = __fadd_rn(cx, __fmul_rn(0.5f, w));
  float y2 = __fadd_rn(cy, __fmul_rn(0.5f, h));
  x1 = fminf(fmaxf(x1, 0.f), IMGSZ);
  y1 = fminf(fmaxf(y1, 0.f), IMGSZ);
  x2 = fminf(fmaxf(x2, 0.f), IMGSZ);
  y2 = fminf(fmaxf(y2, 0.f), IMGSZ);
  ((float4*)boxes)[t] = make_float4(x1, y1, x2, y2);
}

// ---- IoU suppression bitmask (j > i), one thread per 64-bit word ----------
__global__ void iou_kernel(const float* __restrict__ boxes,
                           u64* __restrict__ mask, int B) {
  int t = blockIdx.x * blockDim.x + threadIdx.x;
  if (t >= B * PRE_NMS * NWORDS) return;
  int w = t & (NWORDS - 1);
  int bi = t >> 5;
  int i = bi % PRE_NMS;
  int b = bi / PRE_NMS;
  const float4* bb = (const float4*)boxes + (size_t)b * PRE_NMS;
  float4 A4 = bb[i];
  float area_a = __fmul_rn(__fsub_rn(A4.z, A4.x), __fsub_rn(A4.w, A4.y));
  u64 m = 0;
  int j0 = w << 6;
  int jend = min(j0 + 64, PRE_NMS);
  for (int j = max(j0, i + 1); j < jend; ++j) {
    float4 Bb = bb[j];
    float area_b = __fmul_rn(__fsub_rn(Bb.z, Bb.x), __fsub_rn(Bb.w, Bb.y));
    float ltx = fmaxf(A4.x, Bb.x), lty = fmaxf(A4.y, Bb.y);
    float rbx = fminf(A4.z, Bb.z), rby = fminf(A4.w, Bb.w);
    float iw = fmaxf(__fsub_rn(rbx, ltx), 0.f);
    float ih = fmaxf(__fsub_rn(rby, lty), 0.f);
    float inter = __fmul_rn(iw, ih);
    float denom = __fadd_rn(__fsub_rn(__fadd_rn(area_a, area_b), inter), 1e-9f);
    float iou = inter / denom;
    if (iou > IOU_T) m |= 1ULL << (j - j0);
  }
  mask[t] = m;
}

// ---- NMS scan v3: 256 threads/image, broadcast ds_read diag, no shfl chain
// LDS row stride 33 u64; phase1 reads are uniform-address (broadcast, free).
#define LSTRIDE 33
__global__ __launch_bounds__(256, 1) void nms_scan(
    const u64* __restrict__ mask, u64* __restrict__ keep_g) {
  int b = blockIdx.x;
  int tid = threadIdx.x;
  int wave = tid >> 6, lane = tid & 63;
  __shared__ u64 buf[2][64 * LSTRIDE];   // 2 x 16.5 KiB
  __shared__ u64 s_keep[NWORDS];
  __shared__ u64 s_cur;
  if (tid < NWORDS) s_keep[tid] = (tid == NWORDS - 1) ? 0xFFFFULL : ~0ULL;
  const u64* mb = mask + (size_t)b * PRE_NMS * NWORDS;
  // staging map: thread t -> row r = t>>2 (0..63), words w0..w0+7, w0=(t&3)*8
  int r = tid >> 2;
  int w0 = (tid & 3) * 8;
  uint4 cur0, cur1, cur2, cur3, nx0, nx1, nx2, nx3;
  // load chunk 0
  {
    const uint4* src = (const uint4*)(mb + (size_t)r * NWORDS + w0);
    bool ok = (r < PRE_NMS);
    uint4 z = make_uint4(0, 0, 0, 0);
    cur0 = ok ? src[0] : z; cur1 = ok ? src[1] : z;
    cur2 = ok ? src[2] : z; cur3 = ok ? src[3] : z;
  }
  for (int c = 0; c < NWORDS; ++c) {
    int p = c & 1;
    // store current chunk into buf[p]
    {
      u64* dst = &buf[p][r * LSTRIDE + w0];
      dst[0] = ((u64)cur0.y << 32) | cur0.x;  dst[1] = ((u64)cur0.w << 32) | cur0.z;
      dst[2] = ((u64)cur1.y << 32) | cur1.x;  dst[3] = ((u64)cur1.w << 32) | cur1.z;
      dst[4] = ((u64)cur2.y << 32) | cur2.x;  dst[5] = ((u64)cur2.w << 32) | cur2.z;
      dst[6] = ((u64)cur3.y << 32) | cur3.x;  dst[7] = ((u64)cur3.w << 32) | cur3.z;
    }
    __syncthreads();                     // barrier 1: stores visible
    // prefetch chunk c+1 AFTER the barrier so vmcnt drain overlaps phase1/2
    if (c + 1 < NWORDS) {
      int grow = (c + 1) * 64 + r;
      const uint4* src = (const uint4*)(mb + (size_t)grow * NWORDS + w0);
      bool ok = (grow < PRE_NMS);
      uint4 z = make_uint4(0, 0, 0, 0);
      nx0 = ok ? src[0] : z; nx1 = ok ? src[1] : z;
      nx2 = ok ? src[2] : z; nx3 = ok ? src[3] : z;
    }
    // phase 1: wave 0 resolves the diagonal block serially, register-only
    if (wave == 0) {
      u64 rr[64];
      const u64* base = &buf[p][c];      // row bb -> base[bb*LSTRIDE]
      #pragma unroll
      for (int bb = 0; bb < 64; ++bb)
        rr[bb] = base[bb * LSTRIDE];     // uniform addr -> LDS broadcast
      u64 cur = s_keep[c];
      #pragma unroll
      for (int bb = 0; bb < 64; ++bb) {
        u64 bit = (cur >> bb) & 1ULL;
        cur &= ~(rr[bb] & (0ULL - bit)); // branchless, ~5 ops/step chain
      }
      if (lane == 0) { s_keep[c] = cur; s_cur = cur; }
    }
    __syncthreads();                     // barrier 2: s_cur visible
    // phase 2: 4 waves apply suppression to words w > c
    {
      u64 cur = s_cur;
      bool mine = (cur >> lane) & 1ULL;
      for (int w = c + 1 + wave; w < NWORDS; w += 4) {
        u64 v = mine ? buf[p][lane * LSTRIDE + w] : 0ULL;
        #pragma unroll
        for (int d = 1; d < 64; d <<= 1) v |= __shfl_xor(v, d, 64);
        if (lane == 0) s_keep[w] &= ~v;
      }
    }
    cur0 = nx0; cur1 = nx1; cur2 = nx2; cur3 = nx3;
  }
  __syncthreads();
  if (tid < NWORDS) keep_g[b * NWORDS + tid] = s_keep[tid];
}

// ---- rank kept boxes, emit [box, sigmoid] ---------------------------------
__global__ void write_out(const u64* __restrict__ keep,
                          const float* __restrict__ boxes,
                          const float* __restrict__ logits,
                          float* __restrict__ out) {
  int b = blockIdx.x;
  __shared__ int pre[NWORDS];
  if (threadIdx.x == 0) {
    int acc = 0;
    for (int w = 0; w < NWORDS; ++w) {
      pre[w] = acc;
      acc += __popcll(keep[b * NWORDS + w]);
    }
  }
  __syncthreads();
  for (int i = threadIdx.x; i < PRE_NMS; i += blockDim.x) {
    u64 w = keep[b * NWORDS + (i >> 6)];
    if ((w >> (i & 63)) & 1) {
      int rank = pre[i >> 6] + __popcll(w & ((1ULL << (i & 63)) - 1ULL));
      if (rank < POST_NMS) {
        float4 bx = ((const float4*)boxes)[(size_t)b * PRE_NMS + i];
        float lg = logits[b * PRE_NMS + i];
        float e = (float)exp(-(double)lg);
        float p = 1.0f / (1.0f + e);
        float* o = out + ((size_t)b * POST_NMS + rank) * 5;
        o[0] = bx.x; o[1] = bx.y; o[2] = bx.z; o[3] = bx.w; o[4] = p;
      }
    }
  }
}

extern "C" void kernel_launch(void* const* d_in, const int* in_sizes, int n_in,
                              void* d_out, int out_size, void* d_ws, size_t ws_size,
                              hipStream_t stream) {
  const float* scores  = (const float*)d_in[0];
  const float* deltas  = (const float*)d_in[1];
  const float* anchors = (const float*)d_in[2];
  int A = in_sizes[2] / 4;          // 159882
  int B = in_sizes[0] / A;          // 16

  char* ws = (char*)d_ws;
  size_t off = 0;
  auto alloc = [&](size_t bytes) {
    void* p = ws + off;
    off += (bytes + 255) & ~(size_t)255;
    return p;
  };
  unsigned* ghist    = (unsigned*)alloc((size_t)B * NBINS * 4);
  int*      cand_cnt = (int*)alloc((size_t)B * 4);
  size_t zero_bytes = off;
  int*      T1       = (int*)alloc((size_t)B * 4);
  u64*      cand     = (u64*)alloc((size_t)B * CAP * 8);
  int*      topk_idx = (int*)alloc((size_t)B * PRE_NMS * 4);
  float*    topk_lg  = (float*)alloc((size_t)B * PRE_NMS * 4);
  float*    boxes    = (float*)alloc((size_t)B * PRE_NMS * 16);
  u64*      mask     = (u64*)alloc((size_t)B * PRE_NMS * NWORDS * 8);
  u64*      keep     = (u64*)alloc((size_t)B * NWORDS * 8);

  hipMemsetAsync(d_out, 0, (size_t)out_size * 4, stream);
  hipMemsetAsync(ws, 0, zero_bytes, stream);

  hist_kernel<<<dim3(B, NSLICE), 256, 0, stream>>>(scores, A, ghist);
  thresh1_kernel<<<B, 1024, 0, stream>>>(ghist, T1);
  compact_kernel<<<dim3(B, NSLICE), 256, 0, stream>>>(scores, A, T1, cand, cand_cnt);
  refine_sort_kernel<<<B, 1024, 0, stream>>>(cand, cand_cnt, T1, topk_idx, topk_lg);
  int totalD = B * PRE_NMS;
  decode_kernel<<<(totalD + 255) / 256, 256, 0, stream>>>(deltas, anchors, topk_idx, boxes, A, B);
  int totalI = B * PRE_NMS * NWORDS;
  iou_kernel<<<(totalI + 255) / 256, 256, 0, stream>>>(boxes, mask, B);
  nms_scan<<<B, 256, 0, stream>>>(mask, keep);
  write_out<<<B, 256, 0, stream>>>(keep, boxes, topk_lg, (float*)d_out);
}

// Round 5
// 268.539 us; speedup vs baseline: 3.6762x; 1.4558x over previous
//
#include <hip/hip_runtime.h>
#include <math.h>

#define PRE_NMS 2000
#define POST_NMS 1000
#define IOU_T 0.7f
#define IMGSZ 800.0f
#define CAP 6144            // level-1 candidates per image (expected ~3600)
#define SORTN 2048          // level-2 refined candidates (expected ~2003)
#define NBINS 1024
#define NWORDS 32           // ceil(PRE_NMS/64)
#define NSLICE 16           // blocks per image for hist/compact
#define MROWS 2048          // padded row dim of transposed mask

typedef unsigned long long u64;

__device__ __forceinline__ unsigned key_of(float f) {
    unsigned u = __float_as_uint(f);
    return (u & 0x80000000u) ? ~u : (u | 0x80000000u);
}
__device__ __forceinline__ float inv_key(unsigned k) {
    unsigned u = (k & 0x80000000u) ? (k ^ 0x80000000u) : ~k;
    return __uint_as_float(u);
}

// ---- K1: level-1 histogram (10-bit), 16 slices/image, merge via global atomics
__global__ __launch_bounds__(256) void hist_kernel(
    const float* __restrict__ scores, int A, unsigned* __restrict__ ghist) {
  int b = blockIdx.x, slice = blockIdx.y;
  __shared__ unsigned h[NBINS];
  int tid = threadIdx.x;
  for (int i = tid; i < NBINS; i += 256) h[i] = 0;
  __syncthreads();
  int per = (A + NSLICE - 1) / NSLICE;
  int lo = slice * per, hi = min(lo + per, A);
  const float* sc = scores + (size_t)b * A;
  for (int i = lo + tid; i < hi; i += 256)
    atomicAdd(&h[key_of(sc[i]) >> 22], 1u);
  __syncthreads();
  for (int i = tid; i < NBINS; i += 256)
    if (h[i]) atomicAdd(&ghist[b * NBINS + i], h[i]);
}

// ---- K2: suffix-scan ghist, find level-1 threshold bin T1 ----
__global__ __launch_bounds__(1024) void thresh1_kernel(
    const unsigned* __restrict__ ghist, int* __restrict__ T1) {
  int b = blockIdx.x, tid = threadIdx.x;
  __shared__ unsigned tmp[NBINS];
  __shared__ int s_T;
  unsigned v = ghist[b * NBINS + tid];
  for (int d = 1; d < NBINS; d <<= 1) {
    tmp[tid] = v;
    __syncthreads();
    if (tid + d < NBINS) v += tmp[tid + d];
    __syncthreads();
  }
  tmp[tid] = v;   // count of keys with bin >= tid
  __syncthreads();
  unsigned nextv = (tid < NBINS - 1) ? tmp[tid + 1] : 0u;
  if (v >= PRE_NMS && nextv < PRE_NMS) s_T = tid;
  __syncthreads();
  if (tid == 0) T1[b] = s_T;
}

// ---- K3: compact candidates above T1 (two-phase, 1 atomic/block) ----------
__global__ __launch_bounds__(256) void compact_kernel(
    const float* __restrict__ scores, int A, const int* __restrict__ T1,
    u64* __restrict__ cand, int* __restrict__ cand_cnt) {
  int b = blockIdx.x, slice = blockIdx.y;
  int tid = threadIdx.x;
  int lane = tid & 63, wave = tid >> 6;
  int T = T1[b];
  int per = (A + NSLICE - 1) / NSLICE;
  int lo = slice * per, hi = min(lo + per, A);
  const float* sc = scores + (size_t)b * A;
  int cnt = 0;
  for (int i = lo + tid; i < hi; i += 256)
    cnt += ((int)(key_of(sc[i]) >> 22) >= T);
  int pfx = cnt;
  #pragma unroll
  for (int d = 1; d < 64; d <<= 1) {
    int t2 = __shfl_up(pfx, d, 64);
    if (lane >= d) pfx += t2;
  }
  __shared__ int s_wt[4];
  __shared__ int s_base;
  if (lane == 63) s_wt[wave] = pfx;
  __syncthreads();
  if (tid == 0) {
    int tot = s_wt[0] + s_wt[1] + s_wt[2] + s_wt[3];
    int acc = 0;
    #pragma unroll
    for (int w2 = 0; w2 < 4; ++w2) { int t3 = s_wt[w2]; s_wt[w2] = acc; acc += t3; }
    s_base = atomicAdd(&cand_cnt[b], tot);
  }
  __syncthreads();
  int my_off = s_base + s_wt[wave] + (pfx - cnt);
  u64* cb = cand + (size_t)b * CAP;
  for (int i = lo + tid; i < hi; i += 256) {
    unsigned k = key_of(sc[i]);
    if ((int)(k >> 22) >= T) {
      if (my_off < CAP) cb[my_off] = ((u64)k << 32) | (unsigned)(~i);
      my_off++;
    }
  }
}

// ---- K4: 20-bit threshold refinement + bitonic sort 2048 + emit top-2000 --
__global__ __launch_bounds__(1024) void refine_sort_kernel(
    const u64* __restrict__ cand, const int* __restrict__ cand_cnt,
    const int* __restrict__ T1,
    int* __restrict__ topk_idx, float* __restrict__ topk_logit) {
  int b = blockIdx.x, tid = threadIdx.x;
  int lane = tid & 63;
  __shared__ unsigned h2[NBINS];
  __shared__ unsigned tmp[NBINS];
  __shared__ u64 s[SORTN];
  __shared__ int s_above, s_sel, s_T2;
  int n = min(cand_cnt[b], CAP);
  const u64* cb = cand + (size_t)b * CAP;
  h2[tid] = 0;
  if (tid == 0) { s_above = 0; s_sel = 0; }
  __syncthreads();
  int T1v = T1[b];
  int loc = 0;
  for (int i = tid; i < n; i += 1024) {
    unsigned k = (unsigned)(cb[i] >> 32);
    if ((int)(k >> 22) > T1v) loc++;
    else atomicAdd(&h2[(k >> 12) & 1023], 1u);
  }
  for (int d = 32; d; d >>= 1) loc += __shfl_down(loc, d, 64);
  if (lane == 0 && loc) atomicAdd(&s_above, loc);
  __syncthreads();
  unsigned v = h2[tid];
  for (int d = 1; d < NBINS; d <<= 1) {
    tmp[tid] = v;
    __syncthreads();
    if (tid + d < NBINS) v += tmp[tid + d];
    __syncthreads();
  }
  tmp[tid] = v;
  __syncthreads();
  int above = s_above;
  unsigned nextv = (tid < NBINS - 1) ? tmp[tid + 1] : 0u;
  if (above + (int)v >= PRE_NMS && above + (int)nextv < PRE_NMS) s_T2 = tid;
  __syncthreads();
  unsigned thresh20 = ((unsigned)T1v << 10) | (unsigned)s_T2;
  for (int i = tid; i < SORTN; i += 1024) s[i] = 0ULL;
  __syncthreads();
  for (int i = tid; i < n; i += 1024) {
    u64 cv = cb[i];
    if ((unsigned)(cv >> 44) >= thresh20) {
      int pos = atomicAdd(&s_sel, 1);
      if (pos < SORTN) s[pos] = cv;
    }
  }
  __syncthreads();
  for (int k = 2; k <= SORTN; k <<= 1) {
    for (int j = k >> 1; j > 0; j >>= 1) {
      for (int i = tid; i < SORTN; i += 1024) {
        int l = i ^ j;
        if (l > i) {
          u64 a = s[i], c2 = s[l];
          bool desc = ((i & k) == 0);
          if (desc ? (a < c2) : (a > c2)) { s[i] = c2; s[l] = a; }
        }
      }
      __syncthreads();
    }
  }
  for (int i = tid; i < PRE_NMS; i += 1024) {
    u64 v2 = s[i];
    topk_idx[b * PRE_NMS + i] = (int)(~(unsigned)v2);
    topk_logit[b * PRE_NMS + i] = inv_key((unsigned)(v2 >> 32));
  }
}

// ---- decode boxes (non-contracted fp32, matches numpy op-by-op) -----------
__global__ void decode_kernel(const float* __restrict__ deltas,
                              const float* __restrict__ anchors,
                              const int* __restrict__ topk_idx,
                              float* __restrict__ boxes, int A, int B) {
  int t = blockIdx.x * blockDim.x + threadIdx.x;
  if (t >= B * PRE_NMS) return;
  int b = t / PRE_NMS;
  int a = topk_idx[t];
  float4 dl = ((const float4*)deltas)[(size_t)b * A + a];
  float4 an = ((const float4*)anchors)[a];
  const float CLIP = 4.135166556742356f;  // log(1000/16)
  float wa = __fsub_rn(an.z, an.x);
  float ha = __fsub_rn(an.w, an.y);
  float cxa = __fadd_rn(an.x, __fmul_rn(0.5f, wa));
  float cya = __fadd_rn(an.y, __fmul_rn(0.5f, ha));
  float dw = fminf(dl.z, CLIP), dh = fminf(dl.w, CLIP);
  float cx = __fadd_rn(__fmul_rn(dl.x, wa), cxa);
  float cy = __fadd_rn(__fmul_rn(dl.y, ha), cya);
  float w = __fmul_rn((float)exp((double)dw), wa);
  float h = __fmul_rn((float)exp((double)dh), ha);
  float x1 = __fsub_rn(cx, __fmul_rn(0.5f, w));
  float y1 = __fsub_rn(cy, __fmul_rn(0.5f, h));
  float x2 = __fadd_rn(cx, __fmul_rn(0.5f, w));
  float y2 = __fadd_rn(cy, __fmul_rn(0.5f, h));
  x1 = fminf(fmaxf(x1, 0.f), IMGSZ);
  y1 = fminf(fmaxf(y1, 0.f), IMGSZ);
  x2 = fminf(fmaxf(x2, 0.f), IMGSZ);
  y2 = fminf(fmaxf(y2, 0.f), IMGSZ);
  ((float4*)boxes)[t] = make_float4(x1, y1, x2, y2);
}

// ---- IoU tiles: one wave per 64x64 upper-triangle tile --------------------
// maskT layout: maskT[(b*32 + w)*MROWS + i]  (transposed: word-major).
// Inner loads are LDS broadcasts; output store is coalesced across lanes.
__global__ __launch_bounds__(64) void iou_tile(
    const float* __restrict__ boxes, u64* __restrict__ maskT) {
  int k = blockIdx.x;       // 0..527 -> (ti <= wj) pair
  int b = blockIdx.y;
  int wj = (int)((sqrtf(8.0f * k + 1.0f) - 1.0f) * 0.5f);
  while ((wj + 1) * (wj + 2) / 2 <= k) ++wj;
  while (wj * (wj + 1) / 2 > k) --wj;
  int ti = k - wj * (wj + 1) / 2;
  int lane = threadIdx.x;
  int i = ti * 64 + lane;
  const float4* bb = (const float4*)boxes + (size_t)b * PRE_NMS;
  __shared__ float4 sbox[64];
  int jg = wj * 64 + lane;
  sbox[lane] = bb[min(jg, PRE_NMS - 1)];
  float4 A4 = bb[min(i, PRE_NMS - 1)];
  __syncthreads();
  float area_a = __fmul_rn(__fsub_rn(A4.z, A4.x), __fsub_rn(A4.w, A4.y));
  u64 m = 0;
  #pragma unroll 8
  for (int jj = 0; jj < 64; ++jj) {
    float4 Bb = sbox[jj];                  // uniform address -> broadcast
    float area_b = __fmul_rn(__fsub_rn(Bb.z, Bb.x), __fsub_rn(Bb.w, Bb.y));
    float ltx = fmaxf(A4.x, Bb.x), lty = fmaxf(A4.y, Bb.y);
    float rbx = fminf(A4.z, Bb.z), rby = fminf(A4.w, Bb.w);
    float iw = fmaxf(__fsub_rn(rbx, ltx), 0.f);
    float ih = fmaxf(__fsub_rn(rby, lty), 0.f);
    float inter = __fmul_rn(iw, ih);
    float denom = __fadd_rn(__fsub_rn(__fadd_rn(area_a, area_b), inter), 1e-9f);
    float iou = inter / denom;
    int j = wj * 64 + jj;
    if (j > i && iou > IOU_T) m |= 1ULL << jj;
  }
  maskT[((size_t)b * NWORDS + wj) * MROWS + i] = m;   // coalesced
}

// ---- NMS scan v4: forced-hoist diag loads + row-parallel suppression ------
// LDS buf[w*WSTRIDE + r] (word-major). Phase 1: 64 broadcast ds_reads hoisted
// above the chain via sched_barrier(0) -> pipelined, then ALU-only 64 steps.
// Phase 2: lane l owns word l; 8 independent row-reads per half-wave, OR'd,
// combined via one shfl_xor(32) + one LDS atomicAnd.
#define WSTRIDE 65
__global__ __launch_bounds__(256, 1) void nms_scan(
    const u64* __restrict__ maskT, u64* __restrict__ keep_g) {
  int b = blockIdx.x;
  int tid = threadIdx.x;
  int wave = tid >> 6, lane = tid & 63;
  __shared__ u64 buf[2][NWORDS * WSTRIDE];   // 2 x 16.25 KiB
  __shared__ u64 s_keep[NWORDS];
  __shared__ u64 s_cur;
  if (tid < NWORDS) s_keep[tid] = (tid == NWORDS - 1) ? 0xFFFFULL : ~0ULL;
  const u64* mb = maskT + (size_t)b * NWORDS * MROWS;
  int w = tid >> 3;          // word 0..31
  int sub = tid & 7;         // covers rows sub*8 .. sub*8+7 of the chunk
  uint4 cur0, cur1, cur2, cur3, nx0, nx1, nx2, nx3;
  {
    const uint4* src = (const uint4*)(mb + (size_t)w * MROWS + sub * 8);
    cur0 = src[0]; cur1 = src[1]; cur2 = src[2]; cur3 = src[3];
  }
  for (int c = 0; c < NWORDS; ++c) {
    int p = c & 1;
    {
      u64* dst = &buf[p][w * WSTRIDE + sub * 8];
      dst[0] = ((u64)cur0.y << 32) | cur0.x;  dst[1] = ((u64)cur0.w << 32) | cur0.z;
      dst[2] = ((u64)cur1.y << 32) | cur1.x;  dst[3] = ((u64)cur1.w << 32) | cur1.z;
      dst[4] = ((u64)cur2.y << 32) | cur2.x;  dst[5] = ((u64)cur2.w << 32) | cur2.z;
      dst[6] = ((u64)cur3.y << 32) | cur3.x;  dst[7] = ((u64)cur3.w << 32) | cur3.z;
    }
    __syncthreads();                     // barrier 1: chunk visible in buf[p]
    if (c + 1 < NWORDS) {                // prefetch AFTER barrier -> overlaps
      const uint4* src = (const uint4*)(mb + (size_t)w * MROWS + (c + 1) * 64 + sub * 8);
      nx0 = src[0]; nx1 = src[1]; nx2 = src[2]; nx3 = src[3];
    }
    if (wave == 0) {
      u64 rr[64];
      const u64* base = &buf[p][c * WSTRIDE];   // diag words, contiguous
      #pragma unroll
      for (int bb = 0; bb < 64; ++bb) rr[bb] = base[bb];  // broadcasts
      __builtin_amdgcn_sched_barrier(0);  // keep loads ABOVE the chain
      u64 cur = s_keep[c];
      #pragma unroll
      for (int bb = 0; bb < 64; ++bb) {
        u64 bit = (cur >> bb) & 1ULL;
        cur &= ~(rr[bb] & (0ULL - bit));
      }
      if (lane == 0) { s_keep[c] = cur; s_cur = cur; }
    }
    __syncthreads();                     // barrier 2: s_cur visible
    {
      u64 cur = s_cur;
      int l = lane & 31;                 // word owned
      int h = lane >> 5;
      if (l > c) {
        u64 v = 0;
        int base_bb = wave * 16 + h * 8;
        #pragma unroll
        for (int kk = 0; kk < 8; ++kk) {
          int bbr = base_bb + kk;
          u64 bit = (cur >> bbr) & 1ULL;
          v |= buf[p][l * WSTRIDE + bbr] & (0ULL - bit);
        }
        v |= __shfl_xor(v, 32, 64);      // combine halves
        if (lane < 32 && v) atomicAnd(&s_keep[l], ~v);
      }
    }
    cur0 = nx0; cur1 = nx1; cur2 = nx2; cur3 = nx3;
  }
  __syncthreads();
  if (tid < NWORDS) keep_g[b * NWORDS + tid] = s_keep[tid];
}

// ---- rank kept boxes, emit [box, sigmoid] ---------------------------------
__global__ void write_out(const u64* __restrict__ keep,
                          const float* __restrict__ boxes,
                          const float* __restrict__ logits,
                          float* __restrict__ out) {
  int b = blockIdx.x;
  __shared__ int pre[NWORDS];
  if (threadIdx.x == 0) {
    int acc = 0;
    for (int w = 0; w < NWORDS; ++w) {
      pre[w] = acc;
      acc += __popcll(keep[b * NWORDS + w]);
    }
  }
  __syncthreads();
  for (int i = threadIdx.x; i < PRE_NMS; i += blockDim.x) {
    u64 w = keep[b * NWORDS + (i >> 6)];
    if ((w >> (i & 63)) & 1) {
      int rank = pre[i >> 6] + __popcll(w & ((1ULL << (i & 63)) - 1ULL));
      if (rank < POST_NMS) {
        float4 bx = ((const float4*)boxes)[(size_t)b * PRE_NMS + i];
        float lg = logits[b * PRE_NMS + i];
        float e = (float)exp(-(double)lg);
        float p = 1.0f / (1.0f + e);
        float* o = out + ((size_t)b * POST_NMS + rank) * 5;
        o[0] = bx.x; o[1] = bx.y; o[2] = bx.z; o[3] = bx.w; o[4] = p;
      }
    }
  }
}

extern "C" void kernel_launch(void* const* d_in, const int* in_sizes, int n_in,
                              void* d_out, int out_size, void* d_ws, size_t ws_size,
                              hipStream_t stream) {
  const float* scores  = (const float*)d_in[0];
  const float* deltas  = (const float*)d_in[1];
  const float* anchors = (const float*)d_in[2];
  int A = in_sizes[2] / 4;          // 159882
  int B = in_sizes[0] / A;          // 16

  char* ws = (char*)d_ws;
  size_t off = 0;
  auto alloc = [&](size_t bytes) {
    void* p = ws + off;
    off += (bytes + 255) & ~(size_t)255;
    return p;
  };
  unsigned* ghist    = (unsigned*)alloc((size_t)B * NBINS * 4);
  int*      cand_cnt = (int*)alloc((size_t)B * 4);
  size_t zero_bytes = off;
  int*      T1       = (int*)alloc((size_t)B * 4);
  u64*      cand     = (u64*)alloc((size_t)B * CAP * 8);
  int*      topk_idx = (int*)alloc((size_t)B * PRE_NMS * 4);
  float*    topk_lg  = (float*)alloc((size_t)B * PRE_NMS * 4);
  float*    boxes    = (float*)alloc((size_t)B * PRE_NMS * 16);
  u64*      maskT    = (u64*)alloc((size_t)B * NWORDS * MROWS * 8);
  u64*      keep     = (u64*)alloc((size_t)B * NWORDS * 8);

  hipMemsetAsync(d_out, 0, (size_t)out_size * 4, stream);
  hipMemsetAsync(ws, 0, zero_bytes, stream);

  hist_kernel<<<dim3(B, NSLICE), 256, 0, stream>>>(scores, A, ghist);
  thresh1_kernel<<<B, 1024, 0, stream>>>(ghist, T1);
  compact_kernel<<<dim3(B, NSLICE), 256, 0, stream>>>(scores, A, T1, cand, cand_cnt);
  refine_sort_kernel<<<B, 1024, 0, stream>>>(cand, cand_cnt, T1, topk_idx, topk_lg);
  int totalD = B * PRE_NMS;
  decode_kernel<<<(totalD + 255) / 256, 256, 0, stream>>>(deltas, anchors, topk_idx, boxes, A, B);
  int ntiles = NWORDS * (NWORDS + 1) / 2;   // 528 upper-triangle tiles
  iou_tile<<<dim3(ntiles, B), 64, 0, stream>>>(boxes, maskT);
  nms_scan<<<B, 256, 0, stream>>>(maskT, keep);
  write_out<<<B, 256, 0, stream>>>(keep, boxes, topk_lg, (float*)d_out);
}